// Round 1
// baseline (188.930 us; speedup 1.0000x reference)
//
#include <hip/hip_runtime.h>

// MaskFiller scatter:
//   out[b, keep_ids[b,k], :] = inputs[b,k,:]
//   out[b, mask_ids[b,m], :] = mask_embedding[:]
// B=8, K=4096, M=4096, L=8192, D=512 (fp32).
// keep+mask ids partition [0,L) per batch -> every row written exactly once.
//
// v2: persistent-ish grid (2048 blocks x 256 thr = 8 blk/CU, 32 waves/CU),
//     one WAVE per output row (64 lanes x 2 float4 = 2 KiB row),
//     2 rows unrolled per wave-iteration -> 4 independent loads in flight,
//     embedding hoisted to registers, nontemporal stores (write-once output).

constexpr int B  = 8;
constexpr int K  = 4096;
constexpr int M  = 4096;
constexpr int L  = K + M;   // 8192
constexpr int D  = 512;
constexpr int D4 = D / 4;   // 128 float4 per row

typedef float f32x4 __attribute__((ext_vector_type(4)));

__device__ __forceinline__ void nt_store(float4* p, const float4& v) {
    __builtin_nontemporal_store(*(const f32x4*)&v, (f32x4*)p);
}

__global__ __launch_bounds__(256)
void MaskFiller_scatter_v2(const float4* __restrict__ inputs,
                           const int* __restrict__ mask_ids,
                           const int* __restrict__ keep_ids,
                           const float4* __restrict__ emb,
                           float4* __restrict__ out) {
    const int lane  = threadIdx.x & 63;
    const int wid   = blockIdx.x * (256 / 64) + (threadIdx.x >> 6);
    const int nwave = gridDim.x * (256 / 64);

    // Embedding lives in registers for the whole kernel (2 float4/lane).
    const float4 e0 = emb[lane];
    const float4 e1 = emb[lane + 64];

    // ---- keep rows: flat index r in [0, B*K); b = r/K (K=4096 -> >>12) ----
    // Loads are perfectly sequential across the grid; stores scatter at
    // 2 KiB row granularity (all full cache lines).
    for (int base = wid * 2; base < B * K; base += nwave * 2) {
        const int r0 = base;
        const int r1 = base + 1;
        const int dst0 = keep_ids[r0];           // wave-uniform broadcast load
        const int dst1 = keep_ids[r1];
        const float4* s0 = inputs + (size_t)r0 * D4;
        const float4* s1 = inputs + (size_t)r1 * D4;
        // 4 independent loads in flight per thread (64 B).
        const float4 a0 = s0[lane];
        const float4 a1 = s0[lane + 64];
        const float4 a2 = s1[lane];
        const float4 a3 = s1[lane + 64];
        float4* o0 = out + ((size_t)(r0 >> 12) * L + dst0) * D4;
        float4* o1 = out + ((size_t)(r1 >> 12) * L + dst1) * D4;
        nt_store(o0 + lane,      a0);
        nt_store(o0 + lane + 64, a1);
        nt_store(o1 + lane,      a2);
        nt_store(o1 + lane + 64, a3);
    }

    // ---- mask rows: flat index m in [0, B*M); pure broadcast stores ----
    for (int base = wid * 2; base < B * M; base += nwave * 2) {
        const int m0 = base;
        const int m1 = base + 1;
        const int dst0 = mask_ids[m0];
        const int dst1 = mask_ids[m1];
        float4* o0 = out + ((size_t)(m0 >> 12) * L + dst0) * D4;
        float4* o1 = out + ((size_t)(m1 >> 12) * L + dst1) * D4;
        nt_store(o0 + lane,      e0);
        nt_store(o0 + lane + 64, e1);
        nt_store(o1 + lane,      e0);
        nt_store(o1 + lane + 64, e1);
    }
}

extern "C" void kernel_launch(void* const* d_in, const int* in_sizes, int n_in,
                              void* d_out, int out_size, void* d_ws, size_t ws_size,
                              hipStream_t stream) {
    const float4* inputs   = (const float4*)d_in[0];
    const int*    mask_ids = (const int*)d_in[1];
    const int*    keep_ids = (const int*)d_in[2];
    const float4* emb      = (const float4*)d_in[3];
    // d_in[4] is `axis` (-2), unused.
    float4* out = (float4*)d_out;

    dim3 grid(2048);   // 8 blocks/CU on 256 CUs
    dim3 block(256);   // 4 waves/block; wave = one 2 KiB row slice
    MaskFiller_scatter_v2<<<grid, block, 0, stream>>>(inputs, mask_ids, keep_ids, emb, out);
}

// Round 2
// 185.108 us; speedup vs baseline: 1.0206x; 1.0206x over previous
//
#include <hip/hip_runtime.h>

// MaskFiller scatter:
//   out[b, keep_ids[b,k], :] = inputs[b,k,:]
//   out[b, mask_ids[b,m], :] = mask_embedding[:]
// B=8, K=4096, M=4096, L=8192, D=512 (fp32).
// keep+mask ids partition [0,L) per batch -> every row written exactly once.
//
// v3 = revert to v1 (best measured). Rationale:
//   - bench dur_us = ~156 us constant harness re-poison fills + kernel time
//   - v1 kernel ~30 us vs 29-32 us memory-roofline (202 MB at 6.3-6.9 TB/s)
//   - v2 (persistent grid + nt stores) measured ~3 us slower kernel-side
// One block per output row: 128 threads x float4 = 2 KiB row, perfectly
// coalesced loads AND stores (row-granular scatter = full cache lines).
// 65536 blocks x 2 waves -> ~8192 waves resident, latency fully hidden.

constexpr int B = 8;
constexpr int K = 4096;
constexpr int M = 4096;
constexpr int L = K + M;   // 8192
constexpr int D = 512;
constexpr int D4 = D / 4;  // 128 float4 per row

__global__ __launch_bounds__(128)
void MaskFiller_scatter_kernel(const float4* __restrict__ inputs,
                               const int* __restrict__ mask_ids,
                               const int* __restrict__ keep_ids,
                               const float4* __restrict__ emb,
                               float4* __restrict__ out) {
    const int row = blockIdx.x;      // [0, B*L)
    const int b   = row / L;
    const int r   = row - b * L;     // [0, L)
    const int d4  = threadIdx.x;     // [0, 128)

    float4 v;
    int dst;
    if (r < K) {
        // keep row: copy from inputs
        dst = keep_ids[b * K + r];
        v   = inputs[(size_t)(b * K + r) * D4 + d4];
    } else {
        // mask row: broadcast embedding
        const int m = r - K;
        dst = mask_ids[b * M + m];
        v   = emb[d4];
    }
    out[((size_t)b * L + dst) * D4 + d4] = v;
}

extern "C" void kernel_launch(void* const* d_in, const int* in_sizes, int n_in,
                              void* d_out, int out_size, void* d_ws, size_t ws_size,
                              hipStream_t stream) {
    const float4* inputs   = (const float4*)d_in[0];
    const int*    mask_ids = (const int*)d_in[1];
    const int*    keep_ids = (const int*)d_in[2];
    const float4* emb      = (const float4*)d_in[3];
    // d_in[4] is `axis` (-2), unused.
    float4* out = (float4*)d_out;

    dim3 grid(B * L);   // 65536 blocks, one per output row
    dim3 block(128);    // 128 threads x float4 = 2048 B = one row
    MaskFiller_scatter_kernel<<<grid, block, 0, stream>>>(inputs, mask_ids, keep_ids, emb, out);
}